// Round 11
// baseline (638.994 us; speedup 1.0000x reference)
//
#include <hip/hip_runtime.h>

#define HID 30
#define TS  512
#define NB  16
#define LOG2E 1.44269504088896340736f

typedef __attribute__((ext_vector_type(8))) short bf16x8;
typedef __attribute__((ext_vector_type(4))) float f32x4;

__device__ __forceinline__ float rcp_f(float x){ return __builtin_amdgcn_rcpf(x); }
__device__ __forceinline__ float ex2_f(float x){ return __builtin_amdgcn_exp2f(x); }

__global__ __launch_bounds__(64, 1)
void lstm_mfma_g2(const float* __restrict__ batch,
                  const float* __restrict__ W_ih,
                  const float* __restrict__ W_hh,
                  const float* __restrict__ b_ih,
                  const float* __restrict__ b_hh,
                  const float* __restrict__ W_fc,
                  const float* __restrict__ b_fc,
                  float* __restrict__ out)
{
    __shared__ float xsA[TS * NB];   // 32 KB
    __shared__ float xsB[TS * NB];   // 32 KB

    const int tid  = threadIdx.x;
    const int q    = tid >> 4;      // k-group / row-quadrant 0..3
    const int col  = tid & 15;      // batch col within group
    const int b0   = blockIdx.x * (2 * NB);

    // ---- stage x for both groups: rows 0..31 -> xsA/xsB transposed [t][n]
    #pragma unroll 8
    for (int i = 0; i < 64; ++i) {
        const int flat = i * 64 + tid;        // float4-granule index 0..4095
        const int e    = flat >> 7;           // row 0..31 (uniform per i)
        const int tq   = flat & 127;          // float4 pos within row
        const f32x4 v = ((const f32x4*)(batch + (size_t)(b0 + e) * TS))[tq];
        float* dst = (e < NB) ? xsA : xsB;
        const int ee = e & 15;
        dst[(tq * 4 + 0) * NB + ee] = v[0];
        dst[(tq * 4 + 1) * NB + ee] = v[1];
        dst[(tq * 4 + 2) * NB + ee] = v[2];
        dst[(tq * 4 + 3) * NB + ee] = v[3];
    }

    // ---- A fragments (shared by both groups): identical to round-8 ----
    bf16x8 a_hi[8], a_lo[8];
    #pragma unroll
    for (int mt = 0; mt < 8; ++mt) {
        const int G = mt >> 1, P = mt & 1;
        const int uA = 8 * (col >> 2) + 4 * P + (col & 3);
        const float sG = (G == 2) ? (-2.0f * LOG2E) : (-LOG2E);
        const int R = G * HID + uA;
        #pragma unroll
        for (int jj = 0; jj < 8; ++jj) {
            const int kk = q * 8 + jj;
            float wv = 0.0f;
            if (uA < HID) {
                if (kk < HID)       wv = W_hh[R * HID + kk];
                else if (kk == 30)  wv = b_ih[R] + b_hh[R];
                else                wv = W_ih[R];
            }
            wv *= sG;
            const __bf16 hi = (__bf16)wv;
            const __bf16 lo = (__bf16)(wv - (float)hi);
            a_hi[mt][jj] = (short)__builtin_bit_cast(unsigned short, hi);
            a_lo[mt][jj] = (short)__builtin_bit_cast(unsigned short, lo);
        }
    }

    __builtin_amdgcn_s_waitcnt(0);   // own-wave LDS writes visible

    const float TWOL = 2.0f * LOG2E;
    const f32x4 ZERO4 = {0.0f, 0.0f, 0.0f, 0.0f};

    float cmA[8], hAr[8], cmB[8], hBr[8];
    #pragma unroll
    for (int ii = 0; ii < 8; ++ii) {
        cmA[ii] = 0.0f; hAr[ii] = 0.0f;
        cmB[ii] = 0.0f; hBr[ii] = 0.0f;
    }

    float xvA = xsA[col];
    float xvB = xsB[col];

    for (int t = 0; t < TS; ++t) {
        const int tn = ((t + 1) & (TS - 1)) * NB + col;
        const float xnA = xsA[tn];
        const float xnB = xsB[tn];

        // ---- build B fragments for both groups (r8-verified layout) ----
        bf16x8 bhiA, bloA, bhiB, bloB;
        #pragma unroll
        for (int r2 = 0; r2 < 8; ++r2) {
            const __bf16 ha = (__bf16)hAr[r2];
            const __bf16 la = (__bf16)(hAr[r2] - (float)ha);
            bhiA[r2] = (short)__builtin_bit_cast(unsigned short, ha);
            bloA[r2] = (short)__builtin_bit_cast(unsigned short, la);
            const __bf16 hb = (__bf16)hBr[r2];
            const __bf16 lb = (__bf16)(hBr[r2] - (float)hb);
            bhiB[r2] = (short)__builtin_bit_cast(unsigned short, hb);
            bloB[r2] = (short)__builtin_bit_cast(unsigned short, lb);
        }
        {
            const bool top = (q == 3);
            const __bf16 xhA = (__bf16)xvA;
            const __bf16 xlA = (__bf16)(xvA - (float)xhA);
            bhiA[6] = top ? (short)0x3F80 : bhiA[6];
            bloA[6] = top ? (short)0      : bloA[6];
            bhiA[7] = top ? (short)__builtin_bit_cast(unsigned short, xhA) : bhiA[7];
            bloA[7] = top ? (short)__builtin_bit_cast(unsigned short, xlA) : bloA[7];
            const __bf16 xhB = (__bf16)xvB;
            const __bf16 xlB = (__bf16)(xvB - (float)xhB);
            bhiB[6] = top ? (short)0x3F80 : bhiB[6];
            bloB[6] = top ? (short)0      : bloB[6];
            bhiB[7] = top ? (short)__builtin_bit_cast(unsigned short, xhB) : bhiB[7];
            bloB[7] = top ? (short)__builtin_bit_cast(unsigned short, xlB) : bloB[7];
        }

        // ---- MFMAs: 8 tiles x 3 split products x 2 groups ----
        f32x4 accA[8], accB[8];
        #pragma unroll
        for (int mt = 0; mt < 8; ++mt) {
            f32x4 ta = ZERO4;
            ta = __builtin_amdgcn_mfma_f32_16x16x32_bf16(a_hi[mt], bhiA, ta, 0, 0, 0);
            ta = __builtin_amdgcn_mfma_f32_16x16x32_bf16(a_hi[mt], bloA, ta, 0, 0, 0);
            accA[mt] = __builtin_amdgcn_mfma_f32_16x16x32_bf16(a_lo[mt], bhiA, ta, 0, 0, 0);
            f32x4 tb = ZERO4;
            tb = __builtin_amdgcn_mfma_f32_16x16x32_bf16(a_hi[mt], bhiB, tb, 0, 0, 0);
            tb = __builtin_amdgcn_mfma_f32_16x16x32_bf16(a_hi[mt], bloB, tb, 0, 0, 0);
            accB[mt] = __builtin_amdgcn_mfma_f32_16x16x32_bf16(a_lo[mt], bhiB, tb, 0, 0, 0);
        }

        // ---- activations, group A then B (independent chains interleave) --
        #pragma unroll
        for (int ii = 0; ii < 8; ++ii) {
            const int P = ii >> 2, r = ii & 3;
            const float ai = accA[0 + P][r];
            const float af = accA[2 + P][r];
            const float ag = accA[4 + P][r];
            const float ao = accA[6 + P][r];
            const float ei = ex2_f(ai), eg = ex2_f(ag);
            const float rr = rcp_f((1.0f + ei) * (1.0f + eg));
            const float igm = TWOL * ((eg - 1.0f) * rr);
            const float fv = rcp_f(1.0f + ex2_f(af));
            cmA[ii] = fmaf(fv, cmA[ii], igm);
            const float e  = ex2_f(cmA[ii]);
            const float eo = ex2_f(ao);
            const float r2 = rcp_f((1.0f + e) * (1.0f + eo));
            hAr[ii] = (1.0f - e) * r2;
        }
        #pragma unroll
        for (int ii = 0; ii < 8; ++ii) {
            const int P = ii >> 2, r = ii & 3;
            const float ai = accB[0 + P][r];
            const float af = accB[2 + P][r];
            const float ag = accB[4 + P][r];
            const float ao = accB[6 + P][r];
            const float ei = ex2_f(ai), eg = ex2_f(ag);
            const float rr = rcp_f((1.0f + ei) * (1.0f + eg));
            const float igm = TWOL * ((eg - 1.0f) * rr);
            const float fv = rcp_f(1.0f + ex2_f(af));
            cmB[ii] = fmaf(fv, cmB[ii], igm);
            const float e  = ex2_f(cmB[ii]);
            const float eo = ex2_f(ao);
            const float r2 = rcp_f((1.0f + e) * (1.0f + eo));
            hBr[ii] = (1.0f - e) * r2;
        }

        xvA = xnA;
        xvB = xnB;
    }

    // ---- final projection for both groups ----
    float pA = 0.0f, pB = 0.0f;
    #pragma unroll
    for (int ii = 0; ii < 8; ++ii) {
        const int u = 8 * q + ii;
        const float wf = (u < HID) ? W_fc[u] : 0.0f;
        pA = fmaf(hAr[ii], wf, pA);
        pB = fmaf(hBr[ii], wf, pB);
    }
    pA += __shfl_xor(pA, 16); pA += __shfl_xor(pA, 32);
    pB += __shfl_xor(pB, 16); pB += __shfl_xor(pB, 32);
    if (tid < NB) {
        out[b0 + tid]      = pA + b_fc[0];
        out[b0 + NB + tid] = pB + b_fc[0];
    }
}

extern "C" void kernel_launch(void* const* d_in, const int* in_sizes, int n_in,
                              void* d_out, int out_size, void* d_ws, size_t ws_size,
                              hipStream_t stream) {
    const float* batch = (const float*)d_in[0];
    const float* W_ih  = (const float*)d_in[1];
    const float* W_hh  = (const float*)d_in[2];
    const float* b_ih  = (const float*)d_in[3];
    const float* b_hh  = (const float*)d_in[4];
    const float* W_fc  = (const float*)d_in[5];
    const float* b_fc  = (const float*)d_in[6];
    float* out = (float*)d_out;

    const int blocks = 8192 / (2 * NB);   // 256 single-wave blocks
    lstm_mfma_g2<<<blocks, 64, 0, stream>>>(batch, W_ih, W_hh, b_ih, b_hh,
                                            W_fc, b_fc, out);
}

// Round 12
// 212.574 us; speedup vs baseline: 3.0060x; 3.0060x over previous
//
#include <hip/hip_runtime.h>

#define HID 30
#define TS  512
#define NB  16
#define LOG2E 1.44269504088896340736f
#define XSTR 17    // dwords per t-row of xs (odd: conflict-free column reads)
#define HI   20    // ints per col-row of h buffers (80 B)

typedef __attribute__((ext_vector_type(8))) short bf16x8;
typedef __attribute__((ext_vector_type(4))) float f32x4;

__device__ __forceinline__ float rcp_f(float x){ return __builtin_amdgcn_rcpf(x); }
__device__ __forceinline__ float ex2_f(float x){ return __builtin_amdgcn_exp2f(x); }

__global__ __launch_bounds__(256, 2)
void lstm_mfma_u2(const float* __restrict__ batch,
                  const float* __restrict__ W_ih,
                  const float* __restrict__ W_hh,
                  const float* __restrict__ b_ih,
                  const float* __restrict__ b_hh,
                  const float* __restrict__ W_fc,
                  const float* __restrict__ b_fc,
                  float* __restrict__ out)
{
    __shared__ float xs[TS * XSTR];            // 34.8 KB
    __shared__ int   hhi[2][NB][HI];           // 2 x 1.25 KB (bf16-hi pairs)
    __shared__ int   hlo[2][NB][HI];           // 2 x 1.25 KB (bf16-lo pairs)

    const int tid  = threadIdx.x;
    const int w    = tid >> 6;        // wave: owns units 8w..8w+7
    const int lane = tid & 63;
    const int q    = lane >> 4;       // k-quadrant / C-row-quadrant
    const int col  = lane & 15;       // batch col (B col, C col, A row idx)
    const int b0   = blockIdx.x * NB;

    // ---- stage x (4 waves cooperate; coalesced; odd dword stride) ----
    for (int i = 0; i < 32; ++i) {
        const int flat = i * 256 + tid;
        const int e = flat >> 9, tt = flat & 511;
        xs[tt * XSTR + e] = batch[(size_t)(b0 + e) * TS + tt];
    }
    // ---- zero h buffer 0 ----
    for (int i = tid; i < NB * HI; i += 256) {
        (&hhi[0][0][0])[i] = 0;
        (&hlo[0][0][0])[i] = 0;
    }

    // ---- A fragments: tile tau, row rho=col: gate=rho&3, unit=8w+2*(rho>>2)+tau
    //      k = 8q+jj; k<30: W_hh, k==30: bias, k==31: W_ih; prescaled.
    bf16x8 ahi[2], alo[2];
    #pragma unroll
    for (int tau = 0; tau < 2; ++tau) {
        const int gate = col & 3;                       // i,f,g,o = 0,1,2,3
        const int unit = 8 * w + 2 * (col >> 2) + tau;
        const float sG = (gate == 2) ? (-2.0f * LOG2E) : (-LOG2E);
        const int R = gate * HID + unit;
        #pragma unroll
        for (int jj = 0; jj < 8; ++jj) {
            const int kk = q * 8 + jj;
            float wv = 0.0f;
            if (unit < HID) {
                if (kk < HID)      wv = W_hh[R * HID + kk];
                else if (kk == 30) wv = b_ih[R] + b_hh[R];
                else               wv = W_ih[R];
            }
            wv *= sG;
            const __bf16 hi = (__bf16)wv;
            const __bf16 lo = (__bf16)(wv - (float)hi);
            ahi[tau][jj] = (short)__builtin_bit_cast(unsigned short, hi);
            alo[tau][jj] = (short)__builtin_bit_cast(unsigned short, lo);
        }
    }

    __syncthreads();

    const float TWOL = 2.0f * LOG2E;
    float cm0 = 0.0f, cm1 = 0.0f;     // -2L * c for the lane's two units

#define STEP(T, RB, WB)                                                        \
{                                                                              \
    /* B fragment: h units 8q..8q+7 (+ q==3 overrides k=30,31 -> 1.0, x) */    \
    int4 vhi = *(const int4*)&hhi[RB][col][4 * q];                             \
    int4 vlo = *(const int4*)&hlo[RB][col][4 * q];                             \
    const float xv = xs[(T) * XSTR + col];                                     \
    {                                                                          \
        const __bf16 xh = (__bf16)xv;                                          \
        const __bf16 xl = (__bf16)(xv - (float)xh);                            \
        const unsigned xhb = __builtin_bit_cast(unsigned short, xh);           \
        const unsigned xlb = __builtin_bit_cast(unsigned short, xl);           \
        vhi.w = (q == 3) ? (int)(0x3F80u | (xhb << 16)) : vhi.w;               \
        vlo.w = (q == 3) ? (int)(xlb << 16)             : vlo.w;               \
    }                                                                          \
    const bf16x8 bhi = __builtin_bit_cast(bf16x8, vhi);                        \
    const bf16x8 blo = __builtin_bit_cast(bf16x8, vlo);                        \
    f32x4 a0 = {0.f, 0.f, 0.f, 0.f}, a1 = {0.f, 0.f, 0.f, 0.f};               \
    a0 = __builtin_amdgcn_mfma_f32_16x16x32_bf16(ahi[0], bhi, a0, 0, 0, 0);    \
    a1 = __builtin_amdgcn_mfma_f32_16x16x32_bf16(ahi[1], bhi, a1, 0, 0, 0);    \
    a0 = __builtin_amdgcn_mfma_f32_16x16x32_bf16(ahi[0], blo, a0, 0, 0, 0);    \
    a1 = __builtin_amdgcn_mfma_f32_16x16x32_bf16(ahi[1], blo, a1, 0, 0, 0);    \
    a0 = __builtin_amdgcn_mfma_f32_16x16x32_bf16(alo[0], bhi, a0, 0, 0, 0);    \
    a1 = __builtin_amdgcn_mfma_f32_16x16x32_bf16(alo[1], bhi, a1, 0, 0, 0);    \
    /* in-lane activations: a{0,1} = (ai, af, ag, ao) of units 8w+2q, +1 */    \
    float h0, h1;                                                              \
    {                                                                          \
        const float ei = ex2_f(a0[0]), ef = ex2_f(a0[1]);                      \
        const float eg = ex2_f(a0[2]), eo = ex2_f(a0[3]);                      \
        const float t1 = 1.0f + ei, t2 = 1.0f + eg;                            \
        const float P = t1 * t2, Q = 1.0f + ef;                                \
        const float m1 = (t2 - 2.0f) * Q;                                      \
        const float num = fmaf(TWOL, m1, cm0 * P);                             \
        cm0 = num * rcp_f(P * Q);                                              \
        const float e = ex2_f(cm0);                                            \
        h0 = (1.0f - e) * rcp_f((1.0f + e) * (1.0f + eo));                     \
    }                                                                          \
    {                                                                          \
        const float ei = ex2_f(a1[0]), ef = ex2_f(a1[1]);                      \
        const float eg = ex2_f(a1[2]), eo = ex2_f(a1[3]);                      \
        const float t1 = 1.0f + ei, t2 = 1.0f + eg;                            \
        const float P = t1 * t2, Q = 1.0f + ef;                                \
        const float m1 = (t2 - 2.0f) * Q;                                      \
        const float num = fmaf(TWOL, m1, cm1 * P);                             \
        cm1 = num * rcp_f(P * Q);                                              \
        const float e = ex2_f(cm1);                                            \
        h1 = (1.0f - e) * rcp_f((1.0f + e) * (1.0f + eo));                     \
    }                                                                          \
    /* pack h (hi/lo bf16) for units 8w+2q, 8w+2q+1 -> int slot 4w+q */        \
    {                                                                          \
        const __bf16 h0h = (__bf16)h0;                                         \
        const __bf16 h0l = (__bf16)(h0 - (float)h0h);                          \
        const __bf16 h1h = (__bf16)h1;                                         \
        const __bf16 h1l = (__bf16)(h1 - (float)h1h);                          \
        hhi[WB][col][4 * w + q] =                                              \
            (int)((unsigned)__builtin_bit_cast(unsigned short, h0h) |          \
                 ((unsigned)__builtin_bit_cast(unsigned short, h1h) << 16));   \
        hlo[WB][col][4 * w + q] =                                              \
            (int)((unsigned)__builtin_bit_cast(unsigned short, h0l) |          \
                 ((unsigned)__builtin_bit_cast(unsigned short, h1l) << 16));   \
    }                                                                          \
    __syncthreads();                                                           \
}

    for (int t2 = 0; t2 < TS / 2; ++t2) {
        STEP(2 * t2,     0, 1)
        STEP(2 * t2 + 1, 1, 0)
    }
#undef STEP

    // ---- final projection: h(T) lives in buffer 0 (TS even) ----
    if (tid < NB) {
        const short* hh = (const short*)&hhi[0][tid][0];
        const short* hl = (const short*)&hlo[0][tid][0];
        float acc = b_fc[0];
        #pragma unroll
        for (int u = 0; u < HID; ++u) {
            const float hv =
                (float)__builtin_bit_cast(__bf16, (unsigned short)hh[u]) +
                (float)__builtin_bit_cast(__bf16, (unsigned short)hl[u]);
            acc = fmaf(hv, W_fc[u], acc);
        }
        out[b0 + tid] = acc;
    }
}

extern "C" void kernel_launch(void* const* d_in, const int* in_sizes, int n_in,
                              void* d_out, int out_size, void* d_ws, size_t ws_size,
                              hipStream_t stream) {
    const float* batch = (const float*)d_in[0];
    const float* W_ih  = (const float*)d_in[1];
    const float* W_hh  = (const float*)d_in[2];
    const float* b_ih  = (const float*)d_in[3];
    const float* b_hh  = (const float*)d_in[4];
    const float* W_fc  = (const float*)d_in[5];
    const float* b_fc  = (const float*)d_in[6];
    float* out = (float*)d_out;

    const int blocks = 8192 / NB;   // 512 blocks x 4 waves = 2048 waves
    lstm_mfma_u2<<<blocks, 256, 0, stream>>>(batch, W_ih, W_hh, b_ih, b_hh,
                                             W_fc, b_fc, out);
}

// Round 13
// 186.941 us; speedup vs baseline: 3.4182x; 1.1371x over previous
//
#include <hip/hip_runtime.h>

#define HID 30
#define TS  512
#define NB  16
#define LOG2E 1.44269504088896340736f
#define XSTR 17    // ints per t-row of xs (odd stride)
#define HS   40    // shorts per col-row of h buffers (80 B)

typedef __attribute__((ext_vector_type(8))) short bf16x8;
typedef __attribute__((ext_vector_type(4))) float f32x4;

__device__ __forceinline__ float rcp_f(float x){ return __builtin_amdgcn_rcpf(x); }
__device__ __forceinline__ float ex2_f(float x){ return __builtin_amdgcn_exp2f(x); }

__global__ __launch_bounds__(512, 4)
void lstm_mfma_u1(const float* __restrict__ batch,
                  const float* __restrict__ W_ih,
                  const float* __restrict__ W_hh,
                  const float* __restrict__ b_ih,
                  const float* __restrict__ b_hh,
                  const float* __restrict__ W_fc,
                  const float* __restrict__ b_fc,
                  float* __restrict__ out)
{
    __shared__ int xs[TS * XSTR];                    // 34.8 KB, packed bf16 hi|lo
    __shared__ __align__(16) short hhi[2][NB][HS];   // 2.5 KB
    __shared__ __align__(16) short hlo[2][NB][HS];   // 2.5 KB

    const int tid  = threadIdx.x;
    const int w    = tid >> 6;        // wave 0..7: owns units 4w..4w+3
    const int lane = tid & 63;
    const int q    = lane >> 4;       // k-quadrant / C-row-quadrant
    const int col  = lane & 15;       // batch col
    const int b0   = blockIdx.x * NB;

    // ---- stage x, pre-split into packed bf16 (hi | lo<<16) ----
    #pragma unroll 4
    for (int i = 0; i < NB; ++i) {
        const float v = batch[(size_t)(b0 + i) * TS + tid];
        const __bf16 xh = (__bf16)v;
        const __bf16 xl = (__bf16)(v - (float)xh);
        xs[tid * XSTR + i] =
            (int)((unsigned)__builtin_bit_cast(unsigned short, xh) |
                 ((unsigned)__builtin_bit_cast(unsigned short, xl) << 16));
    }
    // ---- zero h buffers ----
    for (int i = tid; i < 2 * NB * HS / 2; i += 512) {
        ((int*)hhi)[i] = 0;
        ((int*)hlo)[i] = 0;
    }

    // ---- A fragment (1 tile/wave): row rho=col -> gate=col&3, unit=4w+(col>>2)
    //      k = 8q+jj; k<30: W_hh, 30: bias, 31: W_ih; prescaled ----
    bf16x8 ahi, alo;
    {
        const int gate = col & 3;
        const int unit = 4 * w + (col >> 2);
        const float sG = (gate == 2) ? (-2.0f * LOG2E) : (-LOG2E);
        const int R = gate * HID + unit;
        #pragma unroll
        for (int jj = 0; jj < 8; ++jj) {
            const int kk = q * 8 + jj;
            float wv = 0.0f;
            if (unit < HID) {
                if (kk < HID)      wv = W_hh[R * HID + kk];
                else if (kk == 30) wv = b_ih[R] + b_hh[R];
                else               wv = W_ih[R];
            }
            wv *= sG;
            const __bf16 hi = (__bf16)wv;
            const __bf16 lo = (__bf16)(wv - (float)hi);
            ahi[jj] = (short)__builtin_bit_cast(unsigned short, hi);
            alo[jj] = (short)__builtin_bit_cast(unsigned short, lo);
        }
    }

    __syncthreads();

    const float TWOL = 2.0f * LOG2E;
    float cm = 0.0f;                  // -2L * c for the lane's unit

#define STEP(T, RB, WB)                                                        \
{                                                                              \
    int4 vhi = *(const int4*)&hhi[RB][col][8 * q];                             \
    int4 vlo = *(const int4*)&hlo[RB][col][8 * q];                             \
    const unsigned xp = (unsigned)xs[(T) * XSTR + col];                        \
    vhi.w = (q == 3) ? (int)(0x3F80u | (xp << 16)) : vhi.w;                    \
    vlo.w = (q == 3) ? (int)(xp & 0xFFFF0000u)     : vlo.w;                    \
    const bf16x8 bhi = __builtin_bit_cast(bf16x8, vhi);                        \
    const bf16x8 blo = __builtin_bit_cast(bf16x8, vlo);                        \
    f32x4 a = {0.f, 0.f, 0.f, 0.f};                                            \
    a = __builtin_amdgcn_mfma_f32_16x16x32_bf16(ahi, bhi, a, 0, 0, 0);         \
    a = __builtin_amdgcn_mfma_f32_16x16x32_bf16(ahi, blo, a, 0, 0, 0);         \
    a = __builtin_amdgcn_mfma_f32_16x16x32_bf16(alo, bhi, a, 0, 0, 0);         \
    /* a = (ai, af, ag, ao) of unit 4w+q, batch col */                         \
    const float ei = ex2_f(a[0]), ef = ex2_f(a[1]);                            \
    const float eg = ex2_f(a[2]), eo = ex2_f(a[3]);                            \
    const float P  = (1.0f + ei) * (1.0f + eg);                                \
    const float Q  = 1.0f + ef;                                                \
    const float m1 = (eg - 1.0f) * Q;                                          \
    const float num = fmaf(TWOL, m1, cm * P);                                  \
    cm = num * rcp_f(P * Q);                                                   \
    const float e = ex2_f(cm);                                                 \
    const float h = (1.0f - e) * rcp_f((1.0f + e) * (1.0f + eo));              \
    const __bf16 hh = (__bf16)h;                                               \
    const __bf16 hl = (__bf16)(h - (float)hh);                                 \
    hhi[WB][col][4 * w + q] = (short)__builtin_bit_cast(unsigned short, hh);   \
    hlo[WB][col][4 * w + q] = (short)__builtin_bit_cast(unsigned short, hl);   \
    __syncthreads();                                                           \
}

    for (int t2 = 0; t2 < TS / 2; ++t2) {
        STEP(2 * t2,     0, 1)
        STEP(2 * t2 + 1, 1, 0)
    }
#undef STEP

    // ---- final projection: h(T) in buffer 0 ----
    if (tid < NB) {
        const short* hh = &hhi[0][tid][0];
        const short* hl = &hlo[0][tid][0];
        float acc = b_fc[0];
        #pragma unroll
        for (int u = 0; u < HID; ++u) {
            const float hv =
                (float)__builtin_bit_cast(__bf16, (unsigned short)hh[u]) +
                (float)__builtin_bit_cast(__bf16, (unsigned short)hl[u]);
            acc = fmaf(hv, W_fc[u], acc);
        }
        out[b0 + tid] = acc;
    }
}

extern "C" void kernel_launch(void* const* d_in, const int* in_sizes, int n_in,
                              void* d_out, int out_size, void* d_ws, size_t ws_size,
                              hipStream_t stream) {
    const float* batch = (const float*)d_in[0];
    const float* W_ih  = (const float*)d_in[1];
    const float* W_hh  = (const float*)d_in[2];
    const float* b_ih  = (const float*)d_in[3];
    const float* b_hh  = (const float*)d_in[4];
    const float* W_fc  = (const float*)d_in[5];
    const float* b_fc  = (const float*)d_in[6];
    float* out = (float*)d_out;

    const int blocks = 8192 / NB;   // 512 blocks x 8 waves = 4096 waves
    lstm_mfma_u1<<<blocks, 512, 0, stream>>>(batch, W_ih, W_hh, b_ih, b_hh,
                                             W_fc, b_fc, out);
}